// Round 17
// baseline (188.154 us; speedup 1.0000x reference)
//
#include <hip/hip_runtime.h>
#include <stdint.h>

typedef unsigned short u16;
typedef unsigned int u32;
typedef __attribute__((ext_vector_type(8))) short short8;
typedef __attribute__((ext_vector_type(16))) float f32x16;
typedef __attribute__((ext_vector_type(8))) unsigned short u16x8;
typedef __attribute__((ext_vector_type(4))) float float4_t;

__device__ __forceinline__ float b2f(u16 u) { return __uint_as_float(((u32)u) << 16); }
__device__ __forceinline__ u16 f2b(float f) {
  u32 u = __float_as_uint(f);
  u += 0x7fffu + ((u >> 16) & 1u);
  return (u16)(u >> 16);
}

typedef const __attribute__((address_space(1))) void* gas_t;
typedef __attribute__((address_space(3))) void* las_t;
__device__ __forceinline__ void gl_lds16(const void* g, void* l) {
  __builtin_amdgcn_global_load_lds((gas_t)(uintptr_t)g, (las_t)(u32)(uintptr_t)l, 16, 0, 0);
}
__device__ __forceinline__ void barrier_pin() {
  __builtin_amdgcn_sched_barrier(0);
  __builtin_amdgcn_s_barrier();
  __builtin_amdgcn_sched_barrier(0);
}
__device__ __forceinline__ void lgkm0_pin() {
  asm volatile("s_waitcnt lgkmcnt(0)" ::: "memory");
  __builtin_amdgcn_sched_barrier(0);  // rule #18: stop MFMA hoisting above the wait
}

// ---- merged preprocess: x f32->bf16 (blocks 0..4095) + both weight transposes ----
__global__ __launch_bounds__(256) void preprocess(const float* __restrict__ x,
                                                  u16* __restrict__ xb,
                                                  const float* __restrict__ w1,
                                                  u16* __restrict__ d1,
                                                  const float* __restrict__ w2,
                                                  u16* __restrict__ d2) {
  const int id = blockIdx.x;
  if (id < 4096) {
    long i = ((long)id * 256 + threadIdx.x) * 8;
    float4_t v0 = *(const float4_t*)(x + i);
    float4_t v1 = *(const float4_t*)(x + i + 4);
    u16x8 o;
#pragma unroll
    for (int j = 0; j < 4; ++j) { o[j] = f2b(v0[j]); o[4 + j] = f2b(v1[j]); }
    *(u16x8*)(xb + i) = o;
    return;
  }
  // transpose part: 1536 blocks = (bx:48, by:16, z:2)
  const int rid = id - 4096;
  const int zz = rid / 768;
  const int rem = rid - zz * 768;
  const int bxx = rem % 48;
  const int byy = rem / 48;
  if (zz == 1 && bxx >= 16) return;
  const float* src = zz ? w2 : w1;
  u16* dst = zz ? d2 : d1;
  const int C = zz ? 512 : 1536;
  const int R = 512;
  __shared__ float t[32][33];
  const int bx = bxx * 32;
  const int by = byy * 32;
  const int tx = threadIdx.x & 31, ty = threadIdx.x >> 5;
#pragma unroll
  for (int i = 0; i < 32; i += 8)
    t[ty + i][tx] = src[(long)(by + ty + i) * C + bx + tx];
  __syncthreads();
#pragma unroll
  for (int i = 0; i < 32; i += 8)
    dst[(long)(bx + ty + i) * R + by + tx] = f2b(t[tx][ty + i]);
}

// ------------- V slice of qkv [B][N][1536] -> vt [B][512][2048] (bf16) -------------
__global__ __launch_bounds__(512) void tr_v(const u16* __restrict__ qkv,
                                            u16* __restrict__ vt) {
  __shared__ u16 t[64][66];
  const int b = blockIdx.z;
  const int r0 = blockIdx.x * 64;
  const int d0 = blockIdx.y * 64;
  const int tr = threadIdx.x >> 3;
  const int tc = (threadIdx.x & 7) * 8;
  *(u16x8*)&t[tr][tc] =
      *(const u16x8*)&qkv[((long)b * 2048 + r0 + tr) * 1536 + 1024 + d0 + tc];
  __syncthreads();
  u16x8 o;
#pragma unroll
  for (int j = 0; j < 8; ++j) o[j] = t[tc + j][tr];
  *(u16x8*)&vt[((long)b * 512 + d0 + tr) * 2048 + r0 + tc] = o;
}

// ======================= 128x128 2-phase BT-GEMM, 2 blocks/CU =======================
// r9/r16-verified schedule, UNCHANGED:
//   stage(T+1)->buf^1 ; 12 ds_read_b128 tile T ; lgkm0 ; MFMA ; vmcnt(0) ; BAR
// k-slot swizzle (both-sides, key sx=lane&7) + XCD bijective remap.
// NEW (r17): MFMA shape 32x32x16 (µbench 2495 vs 2176 TF). Per-wave 64x32 out =
// 2 frags (mf). Mappings (C-layout m74/m101-verified: col=lane&31,
// row=(reg&3)+8*(reg>>2)+4*(lane>>5)):
//   A-frag mf,kb: row=wr*64+mf*32+(lane&31), slot=(kb*2+(lane>>5))^sx
//   B-frag kb:    row=wc*32+(lane&31),       slot=(kb*2+(lane>>5))^sx
//   (row&7 == lane&7 for all bases -> same sx key; 8-lane groups enumerate all
//    8 bank-quads -> conflict-free, same 12 reads/phase as r16)
// EXP_EPI (QK^T): p=exp2(alpha2*s). ROWSUM_ST (PV): l=rowsum(A) via gated
// ones-MFMA (wc==0 waves of bxi==0 blocks); O_u unnormalized; l->lglob.
// DIVROW (FC): v = acc/l[row] + bias + res.
template <bool OUT_F32, bool BIAS, bool RES, bool EXP_EPI, bool ROWSUM_ST, bool DIVROW>
__global__ __launch_bounds__(512, 4)
void gemm128(const u16* __restrict__ A, const u16* __restrict__ Bt, void* __restrict__ Cv,
             const float* __restrict__ bias, const float* __restrict__ res,
             float* __restrict__ lglob, const float* __restrict__ lin,
             int K, int lda, int ldb, int ldc,
             long aStride, long bStride, long cStride, float alpha) {
  __shared__ u16 As[2][128 * 64];
  __shared__ u16 Bs[2][128 * 64];
  const int tid = threadIdx.x;
  const int wid = tid >> 6, lane = tid & 63;
  const int wr = wid >> 2, wc = wid & 3;
  const int l31 = lane & 31, lg2 = lane >> 5;

  const int gx = gridDim.x, gy = gridDim.y;
  int id = (blockIdx.z * gy + blockIdx.y) * gx + blockIdx.x;
  const int nwg = gx * gy * gridDim.z;
  id = (id & 7) * (nwg >> 3) + (id >> 3);
  const int bxi = id % gx;
  const int t2 = id / gx;
  const int byi = t2 % gy;
  const long z = t2 / gy;

  A += z * aStride;
  Bt += z * bStride;
  const int by = byi * 128;
  const int bx = bxi * 128;

  const bool do_l = ROWSUM_ST && (bxi == 0);  // block-uniform

  f32x16 acc[2] = {};
  f32x16 acc_l[2] = {};  // rowsum (ROWSUM_ST, wc==0, bxi==0)
  short8 ah[2][4], bh[4];
  short8 ones;
#pragma unroll
  for (int j = 0; j < 8; ++j) ones[j] = (short)0x3F80;  // bf16 1.0

  const int w8l = wid * 8 + (lane >> 3);
  const int scol_src = ((lane & 7) ^ (lane >> 3)) * 8;  // pre-swizzled global slot
  const int scol_lin = (lane & 7) * 8;                  // linear LDS slot
  const int nT = K >> 6;
  const int sx = lane & 7;

  auto stage = [&](int kt) {
    const int bb = kt & 1;
    const long kc = (long)kt * 64 + scol_src;
#pragma unroll
    for (int r = 0; r < 2; ++r) {
      const int row = r * 64 + w8l;
      gl_lds16(A + (long)(by + row) * lda + kc, &As[bb][row * 64 + scol_lin]);
    }
#pragma unroll
    for (int r = 0; r < 2; ++r) {
      const int row = r * 64 + w8l;
      gl_lds16(Bt + (long)(bx + row) * ldb + kc, &Bs[bb][row * 64 + scol_lin]);
    }
  };

  // -------- prologue --------
  stage(0);
  asm volatile("s_waitcnt vmcnt(0)" ::: "memory");
  barrier_pin();

  // -------- main loop: one phase per K-tile (schedule unchanged from r16) --------
  for (int T = 0; T < nT; ++T) {
    const int bb = T & 1;
    const bool more = (T + 1) < nT;
    if (more) stage(T + 1);
#pragma unroll
    for (int mf = 0; mf < 2; ++mf)
#pragma unroll
      for (int kb = 0; kb < 4; ++kb)
        ah[mf][kb] = *(const short8*)&As[bb][(wr * 64 + mf * 32 + l31) * 64 +
                                             (((kb * 2 + lg2) ^ sx) * 8)];
#pragma unroll
    for (int kb = 0; kb < 4; ++kb)
      bh[kb] = *(const short8*)&Bs[bb][(wc * 32 + l31) * 64 +
                                       (((kb * 2 + lg2) ^ sx) * 8)];
    lgkm0_pin();
    __builtin_amdgcn_s_setprio(1);
#pragma unroll
    for (int kb = 0; kb < 4; ++kb)
#pragma unroll
      for (int mf = 0; mf < 2; ++mf)
        acc[mf] = __builtin_amdgcn_mfma_f32_32x32x16_bf16(
            ah[mf][kb], bh[kb], acc[mf], 0, 0, 0);
    if constexpr (ROWSUM_ST) {
      if (do_l && wc == 0) {  // wave-uniform; A-frags identical across wc
#pragma unroll
        for (int kb = 0; kb < 4; ++kb)
#pragma unroll
          for (int mf = 0; mf < 2; ++mf)
            acc_l[mf] = __builtin_amdgcn_mfma_f32_32x32x16_bf16(
                ah[mf][kb], ones, acc_l[mf], 0, 0, 0);
      }
    }
    __builtin_amdgcn_s_setprio(0);
    if (more) asm volatile("s_waitcnt vmcnt(0)" ::: "memory");
    barrier_pin();
  }

  // -------- epilogue: row = by+wr*64+mf*32+(reg&3)+8*(reg>>2)+4*lg2 ; col = bx+wc*32+l31 --------
  const int col = bx + wc * 32 + l31;
  if constexpr (ROWSUM_ST) {
    // every col of acc_l holds the row sum; lanes 0 and 32 (col 0) cover all rows
    if (do_l && wc == 0 && l31 == 0) {
#pragma unroll
      for (int mf = 0; mf < 2; ++mf)
#pragma unroll
        for (int reg = 0; reg < 16; ++reg)
          lglob[z * 2048 + by + wr * 64 + mf * 32 + (reg & 3) + 8 * (reg >> 2) + 4 * lg2] =
              acc_l[mf][reg];
    }
  }

  if constexpr (EXP_EPI) {
    u16* C = (u16*)Cv + z * cStride;
#pragma unroll
    for (int mf = 0; mf < 2; ++mf)
#pragma unroll
      for (int reg = 0; reg < 16; ++reg) {
        const long row = by + wr * 64 + mf * 32 + (reg & 3) + 8 * (reg >> 2) + 4 * lg2;
        C[row * (long)ldc + col] = f2b(exp2f(acc[mf][reg] * alpha));
      }
  } else if constexpr (OUT_F32) {
    float* C = (float*)Cv + z * cStride;
#pragma unroll
    for (int mf = 0; mf < 2; ++mf)
#pragma unroll
      for (int reg = 0; reg < 16; ++reg) {
        const long row = by + wr * 64 + mf * 32 + (reg & 3) + 8 * (reg >> 2) + 4 * lg2;
        float v;
        if constexpr (DIVROW) v = acc[mf][reg] * (1.0f / lin[row]);
        else                  v = acc[mf][reg] * alpha;
        if (BIAS) v += bias[col];
        if (RES) v += res[row * (long)ldc + col];
        C[row * (long)ldc + col] = v;
      }
  } else {
    u16* C = (u16*)Cv + z * cStride;
#pragma unroll
    for (int mf = 0; mf < 2; ++mf)
#pragma unroll
      for (int reg = 0; reg < 16; ++reg) {
        const long row = by + wr * 64 + mf * 32 + (reg & 3) + 8 * (reg >> 2) + 4 * lg2;
        float v = acc[mf][reg] * alpha;
        if (BIAS) v += bias[col];
        C[row * (long)ldc + col] = f2b(v);
      }
  }
}

extern "C" void kernel_launch(void* const* d_in, const int* in_sizes, int n_in,
                              void* d_out, int out_size, void* d_ws, size_t ws_size,
                              hipStream_t stream) {
  const float* x = (const float*)d_in[0];      // [8,2048,512]
  const float* w_qkv = (const float*)d_in[1];  // [512,1536]
  const float* b_qkv = (const float*)d_in[2];  // [1536]
  const float* w_fc = (const float*)d_in[3];   // [512,512]
  const float* b_fc = (const float*)d_in[4];   // [512]
  float* out = (float*)d_out;                  // [8,2048,512] f32

  char* ws = (char*)d_ws;
  const long MT = 16384;
  u16* xb = (u16*)(ws);                    // 16 MB  [16384][512]   (reused as attn_out)
  u16* wqkvT = (u16*)(ws + 16777216);      // 1.5 MB [1536][512] (dead after QKV ->
                                           //        l overlays it)
  u16* wfcT = (u16*)(ws + 18350080);       // 0.5 MB [512][512]
  u16* qkv = (u16*)(ws + 18874368);        // 48 MB  [16384][1536]
  u16* vt = (u16*)(ws + 69206016);         // 16 MB  [8][512][2048]
  u16* S = (u16*)(ws + 85983232);          // 64 MB  [8][2048][2048]  (Pu)
  u16* attn = xb;                          // raw O_u (unnormalized)
  float* lvec = (float*)(ws + 16777216);   // 64 KB [16384] row sums (overlays wqkvT)

  // scale * log2(e): exp(scale*s) == exp2(alpha2*s); v_exp_f32 computes 2^x
  const float alpha2 = 0.04419417382415922f * 1.4426950408889634f;

  preprocess<<<4096 + 1536, 256, 0, stream>>>(x, xb, w_qkv, wqkvT, w_fc, wfcT);

  // qkv = x @ w_qkv + b_qkv   [16384 x 1536], K=512
  gemm128<false, true, false, false, false, false><<<dim3(12, 128, 1), 512, 0, stream>>>(
      xb, wqkvT, qkv, b_qkv, nullptr, nullptr, nullptr,
      512, 512, 512, 1536, 0, 0, 0, 1.0f);

  tr_v<<<dim3(32, 8, 8), 512, 0, stream>>>(qkv, vt);

  // Pu = exp(scale * Q @ K^T) per batch [2048 x 2048], K=512
  gemm128<false, false, false, true, false, false><<<dim3(16, 16, 8), 512, 0, stream>>>(
      qkv, qkv + 512, S, nullptr, nullptr, nullptr, nullptr,
      512, 1536, 1536, 2048,
      (long)2048 * 1536, (long)2048 * 1536, (long)2048 * 2048, alpha2);

  // O_u = Pu @ V (unnormalized) per batch [2048 x 512], K=2048; l -> lvec
  gemm128<false, false, false, false, true, false><<<dim3(4, 16, 8), 512, 0, stream>>>(
      S, vt, attn, nullptr, nullptr, lvec, nullptr,
      2048, 2048, 2048, 512,
      (long)2048 * 2048, (long)512 * 2048, (long)2048 * 512, 1.0f);

  // out = (O_u @ w_fc)/l + b_fc + x  [16384 x 512], K=512
  gemm128<true, true, true, false, false, true><<<dim3(4, 128, 1), 512, 0, stream>>>(
      attn, wfcT, out, b_fc, x, nullptr, lvec,
      512, 512, 512, 512, 0, 0, 0, 1.0f);
}

// Round 18
// 158.898 us; speedup vs baseline: 1.1841x; 1.1841x over previous
//
#include <hip/hip_runtime.h>
#include <stdint.h>

typedef unsigned short u16;
typedef unsigned int u32;
typedef __attribute__((ext_vector_type(8))) short short8;
typedef __attribute__((ext_vector_type(4))) float f32x4;
typedef __attribute__((ext_vector_type(8))) unsigned short u16x8;
typedef __attribute__((ext_vector_type(4))) float float4_t;

__device__ __forceinline__ float b2f(u16 u) { return __uint_as_float(((u32)u) << 16); }
__device__ __forceinline__ u16 f2b(float f) {
  u32 u = __float_as_uint(f);
  u += 0x7fffu + ((u >> 16) & 1u);
  return (u16)(u >> 16);
}

typedef const __attribute__((address_space(1))) void* gas_t;
typedef __attribute__((address_space(3))) void* las_t;
__device__ __forceinline__ void gl_lds16(const void* g, void* l) {
  __builtin_amdgcn_global_load_lds((gas_t)(uintptr_t)g, (las_t)(u32)(uintptr_t)l, 16, 0, 0);
}
__device__ __forceinline__ void barrier_pin() {
  __builtin_amdgcn_sched_barrier(0);
  __builtin_amdgcn_s_barrier();
  __builtin_amdgcn_sched_barrier(0);
}
__device__ __forceinline__ void lgkm0_pin() {
  asm volatile("s_waitcnt lgkmcnt(0)" ::: "memory");
  __builtin_amdgcn_sched_barrier(0);  // rule #18: stop MFMA hoisting above the wait
}

// ---- merged preprocess: x f32->bf16 (blocks 0..4095) + both weight transposes ----
__global__ __launch_bounds__(256) void preprocess(const float* __restrict__ x,
                                                  u16* __restrict__ xb,
                                                  const float* __restrict__ w1,
                                                  u16* __restrict__ d1,
                                                  const float* __restrict__ w2,
                                                  u16* __restrict__ d2) {
  const int id = blockIdx.x;
  if (id < 4096) {
    long i = ((long)id * 256 + threadIdx.x) * 8;
    float4_t v0 = *(const float4_t*)(x + i);
    float4_t v1 = *(const float4_t*)(x + i + 4);
    u16x8 o;
#pragma unroll
    for (int j = 0; j < 4; ++j) { o[j] = f2b(v0[j]); o[4 + j] = f2b(v1[j]); }
    *(u16x8*)(xb + i) = o;
    return;
  }
  // transpose part: 1536 blocks = (bx:48, by:16, z:2)
  const int rid = id - 4096;
  const int zz = rid / 768;
  const int rem = rid - zz * 768;
  const int bxx = rem % 48;
  const int byy = rem / 48;
  if (zz == 1 && bxx >= 16) return;
  const float* src = zz ? w2 : w1;
  u16* dst = zz ? d2 : d1;
  const int C = zz ? 512 : 1536;
  const int R = 512;
  __shared__ float t[32][33];
  const int bx = bxx * 32;
  const int by = byy * 32;
  const int tx = threadIdx.x & 31, ty = threadIdx.x >> 5;
#pragma unroll
  for (int i = 0; i < 32; i += 8)
    t[ty + i][tx] = src[(long)(by + ty + i) * C + bx + tx];
  __syncthreads();
#pragma unroll
  for (int i = 0; i < 32; i += 8)
    dst[(long)(bx + ty + i) * R + by + tx] = f2b(t[tx][ty + i]);
}

// ------------- V slice of qkv [B][N][1536] -> vt [B][512][2048] (bf16) -------------
__global__ __launch_bounds__(512) void tr_v(const u16* __restrict__ qkv,
                                            u16* __restrict__ vt) {
  __shared__ u16 t[64][66];
  const int b = blockIdx.z;
  const int r0 = blockIdx.x * 64;
  const int d0 = blockIdx.y * 64;
  const int tr = threadIdx.x >> 3;
  const int tc = (threadIdx.x & 7) * 8;
  *(u16x8*)&t[tr][tc] =
      *(const u16x8*)&qkv[((long)b * 2048 + r0 + tr) * 1536 + 1024 + d0 + tc];
  __syncthreads();
  u16x8 o;
#pragma unroll
  for (int j = 0; j < 8; ++j) o[j] = t[tc + j][tr];
  *(u16x8*)&vt[((long)b * 512 + d0 + tr) * 2048 + r0 + tc] = o;
}

// ======================= 128x128 2-phase BT-GEMM, 2 blocks/CU =======================
// THE VERIFIED WINNER (r11/r15/r16, 160.3us config) — byte-identical loop to r16.
// [r17 lesson: 32x32x16 MFMA is a trap here — its operand layout puts lanes
//  {l,l+8,l+16,l+24} on the same swizzled slot and the 128B row stride makes
//  banks slot-only -> 4-way conflict. 16x16x32's lr-indexed rows avoid it.]
// Phase: stage(T+1)->buf^1 ; 12 ds_read_b128 tile T ; lgkm0 ; 16 MFMA ;
//        vmcnt(0) ; BAR.
// k-slot swizzle (both-sides, key sx=lane&7) + XCD bijective remap.
// EXP_EPI (QK^T): p = exp2(alpha2*s).
// ROWSUM_ST (PV): l = rowsum(A) via gated ones-MFMA on wc==0 waves of bxi==0
//   blocks; O_u stored unnormalized; l->lglob ((O_u/l)@W == (O_u@W)/l).
// DIVROW (FC): epilogue v = acc/l[row] + bias + res.
template <bool OUT_F32, bool BIAS, bool RES, bool EXP_EPI, bool ROWSUM_ST, bool DIVROW>
__global__ __launch_bounds__(512, 4)
void gemm128(const u16* __restrict__ A, const u16* __restrict__ Bt, void* __restrict__ Cv,
             const float* __restrict__ bias, const float* __restrict__ res,
             float* __restrict__ lglob, const float* __restrict__ lin,
             int K, int lda, int ldb, int ldc,
             long aStride, long bStride, long cStride, float alpha) {
  __shared__ u16 As[2][128 * 64];
  __shared__ u16 Bs[2][128 * 64];
  const int tid = threadIdx.x;
  const int wid = tid >> 6, lane = tid & 63;
  const int wr = wid >> 2, wc = wid & 3;
  const int lr = lane & 15, lg = lane >> 4;

  const int gx = gridDim.x, gy = gridDim.y;
  int id = (blockIdx.z * gy + blockIdx.y) * gx + blockIdx.x;
  const int nwg = gx * gy * gridDim.z;
  id = (id & 7) * (nwg >> 3) + (id >> 3);
  const int bxi = id % gx;
  const int t2 = id / gx;
  const int byi = t2 % gy;
  const long z = t2 / gy;

  A += z * aStride;
  Bt += z * bStride;
  const int by = byi * 128;
  const int bx = bxi * 128;

  const bool do_l = ROWSUM_ST && (bxi == 0);  // block-uniform

  f32x4 acc[4][2] = {};
  f32x4 acc_l[4] = {};  // row-sum accumulator (ROWSUM_ST, wc==0 waves, bxi==0)
  short8 ah[4][2], bh[2][2];
  short8 ones;
#pragma unroll
  for (int j = 0; j < 8; ++j) ones[j] = (short)0x3F80;  // bf16 1.0

  const int w8l = wid * 8 + (lane >> 3);
  const int scol_src = ((lane & 7) ^ (lane >> 3)) * 8;  // pre-swizzled global slot
  const int scol_lin = (lane & 7) * 8;                  // linear LDS slot
  const int nT = K >> 6;
  const int sx = lane & 7;

  auto stage = [&](int kt) {
    const int bb = kt & 1;
    const long kc = (long)kt * 64 + scol_src;
#pragma unroll
    for (int r = 0; r < 2; ++r) {
      const int row = r * 64 + w8l;
      gl_lds16(A + (long)(by + row) * lda + kc, &As[bb][row * 64 + scol_lin]);
    }
#pragma unroll
    for (int r = 0; r < 2; ++r) {
      const int row = r * 64 + w8l;
      gl_lds16(Bt + (long)(bx + row) * ldb + kc, &Bs[bb][row * 64 + scol_lin]);
    }
  };

  // -------- prologue --------
  stage(0);
  asm volatile("s_waitcnt vmcnt(0)" ::: "memory");
  barrier_pin();

  // -------- main loop: one phase per K-tile --------
  for (int T = 0; T < nT; ++T) {
    const int bb = T & 1;
    const bool more = (T + 1) < nT;
    if (more) stage(T + 1);
#pragma unroll
    for (int mi = 0; mi < 4; ++mi)
#pragma unroll
      for (int ks = 0; ks < 2; ++ks)
        ah[mi][ks] = *(const short8*)&As[bb][(wr * 64 + mi * 16 + lr) * 64 +
                                             (((ks * 4 + lg) ^ sx) * 8)];
#pragma unroll
    for (int n = 0; n < 2; ++n)
#pragma unroll
      for (int ks = 0; ks < 2; ++ks)
        bh[n][ks] = *(const short8*)&Bs[bb][(wc * 32 + n * 16 + lr) * 64 +
                                            (((ks * 4 + lg) ^ sx) * 8)];
    lgkm0_pin();
    __builtin_amdgcn_s_setprio(1);
#pragma unroll
    for (int mi = 0; mi < 4; ++mi)
#pragma unroll
      for (int n = 0; n < 2; ++n)
#pragma unroll
        for (int ks = 0; ks < 2; ++ks)
          acc[mi][n] = __builtin_amdgcn_mfma_f32_16x16x32_bf16(
              ah[mi][ks], bh[n][ks], acc[mi][n], 0, 0, 0);
    if constexpr (ROWSUM_ST) {
      if (do_l && wc == 0) {  // wave-uniform; A-frags identical across wc
#pragma unroll
        for (int mi = 0; mi < 4; ++mi)
#pragma unroll
          for (int ks = 0; ks < 2; ++ks)
            acc_l[mi] = __builtin_amdgcn_mfma_f32_16x16x32_bf16(
                ah[mi][ks], ones, acc_l[mi], 0, 0, 0);
      }
    }
    __builtin_amdgcn_s_setprio(0);
    if (more) asm volatile("s_waitcnt vmcnt(0)" ::: "memory");
    barrier_pin();
  }

  // -------- epilogue --------
  if constexpr (ROWSUM_ST) {
    // every col of acc_l equals the row sum; rows lg*4+j match epilogue map
    if (do_l && wc == 0 && lr == 0) {
#pragma unroll
      for (int mi = 0; mi < 4; ++mi)
#pragma unroll
        for (int j = 0; j < 4; ++j)
          lglob[z * 2048 + by + wr * 64 + mi * 16 + lg * 4 + j] = acc_l[mi][j];
    }
  }

  if constexpr (EXP_EPI) {
    u16* C = (u16*)Cv + z * cStride;
#pragma unroll
    for (int mi = 0; mi < 4; ++mi)
#pragma unroll
      for (int ni = 0; ni < 2; ++ni)
#pragma unroll
        for (int j = 0; j < 4; ++j) {
          const long row = by + wr * 64 + mi * 16 + lg * 4 + j;
          const int col = bx + wc * 32 + ni * 16 + lr;
          C[row * (long)ldc + col] = f2b(exp2f(acc[mi][ni][j] * alpha));
        }
  } else if constexpr (OUT_F32) {
    float* C = (float*)Cv + z * cStride;
#pragma unroll
    for (int mi = 0; mi < 4; ++mi)
#pragma unroll
      for (int j = 0; j < 4; ++j) {
        const long row = by + wr * 64 + mi * 16 + lg * 4 + j;
        float invl = 1.0f;
        if constexpr (DIVROW) invl = 1.0f / lin[row];
#pragma unroll
        for (int ni = 0; ni < 2; ++ni) {
          const int col = bx + wc * 32 + ni * 16 + lr;
          float v = acc[mi][ni][j] * alpha;
          if constexpr (DIVROW) v = acc[mi][ni][j] * invl;
          if (BIAS) v += bias[col];
          if (RES) v += res[row * (long)ldc + col];
          C[row * (long)ldc + col] = v;
        }
      }
  } else {
    u16* C = (u16*)Cv + z * cStride;
#pragma unroll
    for (int mi = 0; mi < 4; ++mi)
#pragma unroll
      for (int ni = 0; ni < 2; ++ni)
#pragma unroll
        for (int j = 0; j < 4; ++j) {
          const long row = by + wr * 64 + mi * 16 + lg * 4 + j;
          const int col = bx + wc * 32 + ni * 16 + lr;
          float v = acc[mi][ni][j] * alpha;
          if (BIAS) v += bias[col];
          C[row * (long)ldc + col] = f2b(v);
        }
  }
}

extern "C" void kernel_launch(void* const* d_in, const int* in_sizes, int n_in,
                              void* d_out, int out_size, void* d_ws, size_t ws_size,
                              hipStream_t stream) {
  const float* x = (const float*)d_in[0];      // [8,2048,512]
  const float* w_qkv = (const float*)d_in[1];  // [512,1536]
  const float* b_qkv = (const float*)d_in[2];  // [1536]
  const float* w_fc = (const float*)d_in[3];   // [512,512]
  const float* b_fc = (const float*)d_in[4];   // [512]
  float* out = (float*)d_out;                  // [8,2048,512] f32

  char* ws = (char*)d_ws;
  const long MT = 16384;
  u16* xb = (u16*)(ws);                    // 16 MB  [16384][512]   (reused as attn_out)
  u16* wqkvT = (u16*)(ws + 16777216);      // 1.5 MB [1536][512] (dead after QKV ->
                                           //        l overlays it)
  u16* wfcT = (u16*)(ws + 18350080);       // 0.5 MB [512][512]
  u16* qkv = (u16*)(ws + 18874368);        // 48 MB  [16384][1536]
  u16* vt = (u16*)(ws + 69206016);         // 16 MB  [8][512][2048]
  u16* S = (u16*)(ws + 85983232);          // 64 MB  [8][2048][2048]  (Pu)
  u16* attn = xb;                          // raw O_u (unnormalized)
  float* lvec = (float*)(ws + 16777216);   // 64 KB [16384] row sums (overlays wqkvT)

  // scale * log2(e): exp(scale*s) == exp2(alpha2*s); v_exp_f32 computes 2^x
  const float alpha2 = 0.04419417382415922f * 1.4426950408889634f;

  preprocess<<<4096 + 1536, 256, 0, stream>>>(x, xb, w_qkv, wqkvT, w_fc, wfcT);

  // qkv = x @ w_qkv + b_qkv   [16384 x 1536], K=512
  gemm128<false, true, false, false, false, false><<<dim3(12, 128, 1), 512, 0, stream>>>(
      xb, wqkvT, qkv, b_qkv, nullptr, nullptr, nullptr,
      512, 512, 512, 1536, 0, 0, 0, 1.0f);

  tr_v<<<dim3(32, 8, 8), 512, 0, stream>>>(qkv, vt);

  // Pu = exp(scale * Q @ K^T) per batch [2048 x 2048], K=512
  gemm128<false, false, false, true, false, false><<<dim3(16, 16, 8), 512, 0, stream>>>(
      qkv, qkv + 512, S, nullptr, nullptr, nullptr, nullptr,
      512, 1536, 1536, 2048,
      (long)2048 * 1536, (long)2048 * 1536, (long)2048 * 2048, alpha2);

  // O_u = Pu @ V (unnormalized) per batch [2048 x 512], K=2048; l -> lvec
  gemm128<false, false, false, false, true, false><<<dim3(4, 16, 8), 512, 0, stream>>>(
      S, vt, attn, nullptr, nullptr, lvec, nullptr,
      2048, 2048, 2048, 512,
      (long)2048 * 2048, (long)512 * 2048, (long)2048 * 512, 1.0f);

  // out = (O_u @ w_fc)/l + b_fc + x  [16384 x 512], K=512
  gemm128<true, true, true, false, false, true><<<dim3(4, 128, 1), 512, 0, stream>>>(
      attn, wfcT, out, b_fc, x, nullptr, lvec,
      512, 512, 512, 512, 0, 0, 0, 1.0f);
}

// Round 19
// 158.213 us; speedup vs baseline: 1.1892x; 1.0043x over previous
//
#include <hip/hip_runtime.h>
#include <stdint.h>

typedef unsigned short u16;
typedef unsigned int u32;
typedef __attribute__((ext_vector_type(8))) short short8;
typedef __attribute__((ext_vector_type(4))) float f32x4;
typedef __attribute__((ext_vector_type(8))) unsigned short u16x8;
typedef __attribute__((ext_vector_type(4))) float float4_t;

__device__ __forceinline__ float b2f(u16 u) { return __uint_as_float(((u32)u) << 16); }
__device__ __forceinline__ u16 f2b(float f) {
  u32 u = __float_as_uint(f);
  u += 0x7fffu + ((u >> 16) & 1u);
  return (u16)(u >> 16);
}

typedef const __attribute__((address_space(1))) void* gas_t;
typedef __attribute__((address_space(3))) void* las_t;
__device__ __forceinline__ void gl_lds16(const void* g, void* l) {
  __builtin_amdgcn_global_load_lds((gas_t)(uintptr_t)g, (las_t)(u32)(uintptr_t)l, 16, 0, 0);
}
__device__ __forceinline__ void barrier_pin() {
  __builtin_amdgcn_sched_barrier(0);
  __builtin_amdgcn_s_barrier();
  __builtin_amdgcn_sched_barrier(0);
}

// ---- merged preprocess: x f32->bf16 (blocks 0..4095) + both weight transposes ----
__global__ __launch_bounds__(256) void preprocess(const float* __restrict__ x,
                                                  u16* __restrict__ xb,
                                                  const float* __restrict__ w1,
                                                  u16* __restrict__ d1,
                                                  const float* __restrict__ w2,
                                                  u16* __restrict__ d2) {
  const int id = blockIdx.x;
  if (id < 4096) {
    long i = ((long)id * 256 + threadIdx.x) * 8;
    float4_t v0 = *(const float4_t*)(x + i);
    float4_t v1 = *(const float4_t*)(x + i + 4);
    u16x8 o;
#pragma unroll
    for (int j = 0; j < 4; ++j) { o[j] = f2b(v0[j]); o[4 + j] = f2b(v1[j]); }
    *(u16x8*)(xb + i) = o;
    return;
  }
  // transpose part: 1536 blocks = (bx:48, by:16, z:2)
  const int rid = id - 4096;
  const int zz = rid / 768;
  const int rem = rid - zz * 768;
  const int bxx = rem % 48;
  const int byy = rem / 48;
  if (zz == 1 && bxx >= 16) return;
  const float* src = zz ? w2 : w1;
  u16* dst = zz ? d2 : d1;
  const int C = zz ? 512 : 1536;
  const int R = 512;
  __shared__ float t[32][33];
  const int bx = bxx * 32;
  const int by = byy * 32;
  const int tx = threadIdx.x & 31, ty = threadIdx.x >> 5;
#pragma unroll
  for (int i = 0; i < 32; i += 8)
    t[ty + i][tx] = src[(long)(by + ty + i) * C + bx + tx];
  __syncthreads();
#pragma unroll
  for (int i = 0; i < 32; i += 8)
    dst[(long)(bx + ty + i) * R + by + tx] = f2b(t[tx][ty + i]);
}

// ------------- V slice of qkv [B][N][1536] -> vt [B][512][2048] (bf16) -------------
__global__ __launch_bounds__(512) void tr_v(const u16* __restrict__ qkv,
                                            u16* __restrict__ vt) {
  __shared__ u16 t[64][66];
  const int b = blockIdx.z;
  const int r0 = blockIdx.x * 64;
  const int d0 = blockIdx.y * 64;
  const int tr = threadIdx.x >> 3;
  const int tc = (threadIdx.x & 7) * 8;
  *(u16x8*)&t[tr][tc] =
      *(const u16x8*)&qkv[((long)b * 2048 + r0 + tr) * 1536 + 1024 + d0 + tc];
  __syncthreads();
  u16x8 o;
#pragma unroll
  for (int j = 0; j < 8; ++j) o[j] = t[tc + j][tr];
  *(u16x8*)&vt[((long)b * 512 + d0 + tr) * 2048 + r0 + tc] = o;
}

// ======================= 128x128 2-phase BT-GEMM, 2 blocks/CU =======================
// r18 winner with ONE change: the lgkmcnt(0)-drain pin between ds_reads and
// MFMAs is REMOVED. The reads are plain C++ loads, so the compiler emits
// fine-grained lgkmcnt(N) waits and interleaves the first MFMAs under the tail
// reads' latency (the m97-verified behavior); the full drain serialized
// 12-read-issue -> ~120cyc wait -> MFMA in barrier-lockstep every phase.
// B-frag reads are ordered first so MFMA 0's operands are among the earliest
// returns. WAR safety unchanged: the last MFMA consumes the last read, so all
// reads retired before the wave reaches the phase-end barrier; vmcnt asm
// ("memory") + sched_barrier'd s_barrier still fence cross-phase LDS reuse.
// [r17 lesson: 32x32x16 MFMA = 4-way LDS conflict trap here; stay 16x16x32.]
// Phase: stage(T+1)->buf^1 ; 12 ds_read_b128 tile T ; 16 MFMA ; vmcnt(0) ; BAR.
// k-slot swizzle (both-sides, key sx=lane&7) + XCD bijective remap.
// EXP_EPI (QK^T): p = exp2(alpha2*s).
// ROWSUM_ST (PV): l = rowsum(A) via gated ones-MFMA on wc==0 waves of bxi==0
//   blocks; O_u stored unnormalized; l->lglob ((O_u/l)@W == (O_u@W)/l).
// DIVROW (FC): epilogue v = acc/l[row] + bias + res.
template <bool OUT_F32, bool BIAS, bool RES, bool EXP_EPI, bool ROWSUM_ST, bool DIVROW>
__global__ __launch_bounds__(512, 4)
void gemm128(const u16* __restrict__ A, const u16* __restrict__ Bt, void* __restrict__ Cv,
             const float* __restrict__ bias, const float* __restrict__ res,
             float* __restrict__ lglob, const float* __restrict__ lin,
             int K, int lda, int ldb, int ldc,
             long aStride, long bStride, long cStride, float alpha) {
  __shared__ u16 As[2][128 * 64];
  __shared__ u16 Bs[2][128 * 64];
  const int tid = threadIdx.x;
  const int wid = tid >> 6, lane = tid & 63;
  const int wr = wid >> 2, wc = wid & 3;
  const int lr = lane & 15, lg = lane >> 4;

  const int gx = gridDim.x, gy = gridDim.y;
  int id = (blockIdx.z * gy + blockIdx.y) * gx + blockIdx.x;
  const int nwg = gx * gy * gridDim.z;
  id = (id & 7) * (nwg >> 3) + (id >> 3);
  const int bxi = id % gx;
  const int t2 = id / gx;
  const int byi = t2 % gy;
  const long z = t2 / gy;

  A += z * aStride;
  Bt += z * bStride;
  const int by = byi * 128;
  const int bx = bxi * 128;

  const bool do_l = ROWSUM_ST && (bxi == 0);  // block-uniform

  f32x4 acc[4][2] = {};
  f32x4 acc_l[4] = {};  // row-sum accumulator (ROWSUM_ST, wc==0 waves, bxi==0)
  short8 ah[4][2], bh[2][2];
  short8 ones;
#pragma unroll
  for (int j = 0; j < 8; ++j) ones[j] = (short)0x3F80;  // bf16 1.0

  const int w8l = wid * 8 + (lane >> 3);
  const int scol_src = ((lane & 7) ^ (lane >> 3)) * 8;  // pre-swizzled global slot
  const int scol_lin = (lane & 7) * 8;                  // linear LDS slot
  const int nT = K >> 6;
  const int sx = lane & 7;

  auto stage = [&](int kt) {
    const int bb = kt & 1;
    const long kc = (long)kt * 64 + scol_src;
#pragma unroll
    for (int r = 0; r < 2; ++r) {
      const int row = r * 64 + w8l;
      gl_lds16(A + (long)(by + row) * lda + kc, &As[bb][row * 64 + scol_lin]);
    }
#pragma unroll
    for (int r = 0; r < 2; ++r) {
      const int row = r * 64 + w8l;
      gl_lds16(Bt + (long)(bx + row) * ldb + kc, &Bs[bb][row * 64 + scol_lin]);
    }
  };

  // -------- prologue --------
  stage(0);
  asm volatile("s_waitcnt vmcnt(0)" ::: "memory");
  barrier_pin();

  // -------- main loop: one phase per K-tile --------
  for (int T = 0; T < nT; ++T) {
    const int bb = T & 1;
    const bool more = (T + 1) < nT;
    if (more) stage(T + 1);
    // B-frags first: MFMA 0's operands are early returns -> compiler waits at
    // a high lgkmcnt and overlaps the remaining reads under MFMA issue.
#pragma unroll
    for (int n = 0; n < 2; ++n)
#pragma unroll
      for (int ks = 0; ks < 2; ++ks)
        bh[n][ks] = *(const short8*)&Bs[bb][(wc * 32 + n * 16 + lr) * 64 +
                                            (((ks * 4 + lg) ^ sx) * 8)];
#pragma unroll
    for (int mi = 0; mi < 4; ++mi)
#pragma unroll
      for (int ks = 0; ks < 2; ++ks)
        ah[mi][ks] = *(const short8*)&As[bb][(wr * 64 + mi * 16 + lr) * 64 +
                                             (((ks * 4 + lg) ^ sx) * 8)];
    __builtin_amdgcn_s_setprio(1);
#pragma unroll
    for (int mi = 0; mi < 4; ++mi)
#pragma unroll
      for (int n = 0; n < 2; ++n)
#pragma unroll
        for (int ks = 0; ks < 2; ++ks)
          acc[mi][n] = __builtin_amdgcn_mfma_f32_16x16x32_bf16(
              ah[mi][ks], bh[n][ks], acc[mi][n], 0, 0, 0);
    if constexpr (ROWSUM_ST) {
      if (do_l && wc == 0) {  // wave-uniform; A-frags identical across wc
#pragma unroll
        for (int mi = 0; mi < 4; ++mi)
#pragma unroll
          for (int ks = 0; ks < 2; ++ks)
            acc_l[mi] = __builtin_amdgcn_mfma_f32_16x16x32_bf16(
                ah[mi][ks], ones, acc_l[mi], 0, 0, 0);
      }
    }
    __builtin_amdgcn_s_setprio(0);
    if (more) asm volatile("s_waitcnt vmcnt(0)" ::: "memory");
    barrier_pin();
  }

  // -------- epilogue --------
  if constexpr (ROWSUM_ST) {
    // every col of acc_l equals the row sum; rows lg*4+j match epilogue map
    if (do_l && wc == 0 && lr == 0) {
#pragma unroll
      for (int mi = 0; mi < 4; ++mi)
#pragma unroll
        for (int j = 0; j < 4; ++j)
          lglob[z * 2048 + by + wr * 64 + mi * 16 + lg * 4 + j] = acc_l[mi][j];
    }
  }

  if constexpr (EXP_EPI) {
    u16* C = (u16*)Cv + z * cStride;
#pragma unroll
    for (int mi = 0; mi < 4; ++mi)
#pragma unroll
      for (int ni = 0; ni < 2; ++ni)
#pragma unroll
        for (int j = 0; j < 4; ++j) {
          const long row = by + wr * 64 + mi * 16 + lg * 4 + j;
          const int col = bx + wc * 32 + ni * 16 + lr;
          C[row * (long)ldc + col] = f2b(exp2f(acc[mi][ni][j] * alpha));
        }
  } else if constexpr (OUT_F32) {
    float* C = (float*)Cv + z * cStride;
#pragma unroll
    for (int mi = 0; mi < 4; ++mi)
#pragma unroll
      for (int j = 0; j < 4; ++j) {
        const long row = by + wr * 64 + mi * 16 + lg * 4 + j;
        float invl = 1.0f;
        if constexpr (DIVROW) invl = 1.0f / lin[row];
#pragma unroll
        for (int ni = 0; ni < 2; ++ni) {
          const int col = bx + wc * 32 + ni * 16 + lr;
          float v = acc[mi][ni][j] * alpha;
          if constexpr (DIVROW) v = acc[mi][ni][j] * invl;
          if (BIAS) v += bias[col];
          if (RES) v += res[row * (long)ldc + col];
          C[row * (long)ldc + col] = v;
        }
      }
  } else {
    u16* C = (u16*)Cv + z * cStride;
#pragma unroll
    for (int mi = 0; mi < 4; ++mi)
#pragma unroll
      for (int ni = 0; ni < 2; ++ni)
#pragma unroll
        for (int j = 0; j < 4; ++j) {
          const long row = by + wr * 64 + mi * 16 + lg * 4 + j;
          const int col = bx + wc * 32 + ni * 16 + lr;
          float v = acc[mi][ni][j] * alpha;
          if (BIAS) v += bias[col];
          C[row * (long)ldc + col] = f2b(v);
        }
  }
}

extern "C" void kernel_launch(void* const* d_in, const int* in_sizes, int n_in,
                              void* d_out, int out_size, void* d_ws, size_t ws_size,
                              hipStream_t stream) {
  const float* x = (const float*)d_in[0];      // [8,2048,512]
  const float* w_qkv = (const float*)d_in[1];  // [512,1536]
  const float* b_qkv = (const float*)d_in[2];  // [1536]
  const float* w_fc = (const float*)d_in[3];   // [512,512]
  const float* b_fc = (const float*)d_in[4];   // [512]
  float* out = (float*)d_out;                  // [8,2048,512] f32

  char* ws = (char*)d_ws;
  const long MT = 16384;
  u16* xb = (u16*)(ws);                    // 16 MB  [16384][512]   (reused as attn_out)
  u16* wqkvT = (u16*)(ws + 16777216);      // 1.5 MB [1536][512] (dead after QKV ->
                                           //        l overlays it)
  u16* wfcT = (u16*)(ws + 18350080);       // 0.5 MB [512][512]
  u16* qkv = (u16*)(ws + 18874368);        // 48 MB  [16384][1536]
  u16* vt = (u16*)(ws + 69206016);         // 16 MB  [8][512][2048]
  u16* S = (u16*)(ws + 85983232);          // 64 MB  [8][2048][2048]  (Pu)
  u16* attn = xb;                          // raw O_u (unnormalized)
  float* lvec = (float*)(ws + 16777216);   // 64 KB [16384] row sums (overlays wqkvT)

  // scale * log2(e): exp(scale*s) == exp2(alpha2*s); v_exp_f32 computes 2^x
  const float alpha2 = 0.04419417382415922f * 1.4426950408889634f;

  preprocess<<<4096 + 1536, 256, 0, stream>>>(x, xb, w_qkv, wqkvT, w_fc, wfcT);

  // qkv = x @ w_qkv + b_qkv   [16384 x 1536], K=512
  gemm128<false, true, false, false, false, false><<<dim3(12, 128, 1), 512, 0, stream>>>(
      xb, wqkvT, qkv, b_qkv, nullptr, nullptr, nullptr,
      512, 512, 512, 1536, 0, 0, 0, 1.0f);

  tr_v<<<dim3(32, 8, 8), 512, 0, stream>>>(qkv, vt);

  // Pu = exp(scale * Q @ K^T) per batch [2048 x 2048], K=512
  gemm128<false, false, false, true, false, false><<<dim3(16, 16, 8), 512, 0, stream>>>(
      qkv, qkv + 512, S, nullptr, nullptr, nullptr, nullptr,
      512, 1536, 1536, 2048,
      (long)2048 * 1536, (long)2048 * 1536, (long)2048 * 2048, alpha2);

  // O_u = Pu @ V (unnormalized) per batch [2048 x 512], K=2048; l -> lvec
  gemm128<false, false, false, false, true, false><<<dim3(4, 16, 8), 512, 0, stream>>>(
      S, vt, attn, nullptr, nullptr, lvec, nullptr,
      2048, 2048, 2048, 512,
      (long)2048 * 2048, (long)512 * 2048, (long)2048 * 512, 1.0f);

  // out = (O_u @ w_fc)/l + b_fc + x  [16384 x 512], K=512
  gemm128<true, true, true, false, false, true><<<dim3(4, 128, 1), 512, 0, stream>>>(
      attn, wfcT, out, b_fc, x, nullptr, lvec,
      512, 512, 512, 512, 0, 0, 0, 1.0f);
}